// Round 1
// baseline (436.715 us; speedup 1.0000x reference)
//
#include <hip/hip_runtime.h>

// out[b,s,e] = cos(x[b,s,e]) * cos(params[(e)*3])   (params shape [16,64,3], angle 0)
// E = 1024 = 256 threads * float4  -> one block-iteration per token,
// thread t's 4 ry values are loop-invariant.

#define EMBED 1024

__global__ __launch_bounds__(256) void qa_cos_kernel(const float* __restrict__ x,
                                                     const float* __restrict__ params,
                                                     float* __restrict__ out,
                                                     int n_tokens) {
    const int t = threadIdx.x;      // 0..255
    const int e0 = t << 2;          // embed base index for this thread

    // Hoisted per-thread rotation factors: cos(params[e,0]) for e = e0..e0+3.
    // params stride over embed index is 3 floats (last dim of [H,D,3]).
    const float r0 = __cosf(params[(e0 + 0) * 3]);
    const float r1 = __cosf(params[(e0 + 1) * 3]);
    const float r2 = __cosf(params[(e0 + 2) * 3]);
    const float r3 = __cosf(params[(e0 + 3) * 3]);

    for (int tok = blockIdx.x; tok < n_tokens; tok += gridDim.x) {
        const float4* __restrict__ xin  = (const float4*)(x   + (size_t)tok * EMBED) + t;
        float4*       __restrict__ outp = (float4*)      (out + (size_t)tok * EMBED) + t;
        float4 v = *xin;
        float4 o;
        o.x = __cosf(v.x) * r0;
        o.y = __cosf(v.y) * r1;
        o.z = __cosf(v.z) * r2;
        o.w = __cosf(v.w) * r3;
        *outp = o;
    }
}

extern "C" void kernel_launch(void* const* d_in, const int* in_sizes, int n_in,
                              void* d_out, int out_size, void* d_ws, size_t ws_size,
                              hipStream_t stream) {
    const float* x      = (const float*)d_in[0];   // [8, 8192, 1024] fp32
    const float* params = (const float*)d_in[1];   // [16, 64, 3] fp32
    float* out          = (float*)d_out;           // [8, 8192, 1024] fp32

    const int n_tokens = in_sizes[0] / EMBED;      // 65536

    // 2048 blocks = 8 blocks/CU at 4 waves/block -> full 32-wave occupancy,
    // each block grid-strides ~32 tokens, amortizing the ry cosines.
    const int grid = 2048;
    qa_cos_kernel<<<grid, 256, 0, stream>>>(x, params, out, n_tokens);
}

// Round 2
// 415.493 us; speedup vs baseline: 1.0511x; 1.0511x over previous
//
#include <hip/hip_runtime.h>

// out[b,s,e] = cos(x[b,s,e]) * cos(params[e_h, e_d, 0])  — pure elementwise.
// E = 1024 floats = 256 threads * float4 -> thread t always owns embed slots
// 4t..4t+3, so its cos(param) factors are loop-invariant.
// Memory floor: 268 MB read + 268 MB write = 536 MB -> ~85 us @ 6.3 TB/s.

#define EMBED 1024
#define TOK_PER_IT 4   // tokens per block-iteration: 4 independent loads in flight

typedef float vfloat4 __attribute__((ext_vector_type(4)));

__global__ __launch_bounds__(256) void qa_cos_kernel(const float* __restrict__ x,
                                                     const float* __restrict__ params,
                                                     float* __restrict__ out,
                                                     int n_tokens) {
    const int t = threadIdx.x;      // 0..255
    const int e0 = t << 2;          // embed base index for this thread

    // Loop-invariant rotation factors (params last-dim stride = 3, angle 0).
    const float r0 = __cosf(params[(e0 + 0) * 3]);
    const float r1 = __cosf(params[(e0 + 1) * 3]);
    const float r2 = __cosf(params[(e0 + 2) * 3]);
    const float r3 = __cosf(params[(e0 + 3) * 3]);

    // n_tokens (65536) divides evenly by gridDim.x * TOK_PER_IT (2048*4=8192).
    const int step = gridDim.x * TOK_PER_IT;
    for (int tok = blockIdx.x * TOK_PER_IT; tok < n_tokens; tok += step) {
        const vfloat4* __restrict__ xin = (const vfloat4*)(x + (size_t)tok * EMBED) + t;
        vfloat4*       __restrict__ ob  = (vfloat4*)(out + (size_t)tok * EMBED) + t;

        vfloat4 v[TOK_PER_IT];
#pragma unroll
        for (int j = 0; j < TOK_PER_IT; ++j)           // 4 independent 16B loads,
            v[j] = __builtin_nontemporal_load(xin + j * (EMBED / 4));  // all in flight

#pragma unroll
        for (int j = 0; j < TOK_PER_IT; ++j) {
            vfloat4 o;
            o.x = __cosf(v[j].x) * r0;
            o.y = __cosf(v[j].y) * r1;
            o.z = __cosf(v[j].z) * r2;
            o.w = __cosf(v[j].w) * r3;
            __builtin_nontemporal_store(o, ob + j * (EMBED / 4));
        }
    }
}

extern "C" void kernel_launch(void* const* d_in, const int* in_sizes, int n_in,
                              void* d_out, int out_size, void* d_ws, size_t ws_size,
                              hipStream_t stream) {
    const float* x      = (const float*)d_in[0];   // [8, 8192, 1024] fp32
    const float* params = (const float*)d_in[1];   // [16, 64, 3] fp32
    float* out          = (float*)d_out;           // [8, 8192, 1024] fp32

    const int n_tokens = in_sizes[0] / EMBED;      // 65536

    // 2048 blocks = 8 blocks/CU (32 waves/CU), 8 iterations of 4 tokens each.
    const int grid = 2048;
    qa_cos_kernel<<<grid, 256, 0, stream>>>(x, params, out, n_tokens);
}